// Round 2
// 977.896 us; speedup vs baseline: 1.1075x; 1.1075x over previous
//
#include <hip/hip_runtime.h>
#include <hip/hip_bf16.h>
#include <math.h>

#define VOCAB 50257
#define NCLS 20
#define EDIM 64
#define HDIM 64
#define BATCH 128
#define TLEN 2048

typedef float v2f __attribute__((ext_vector_type(2)));

// Static device scratch: no dependence on ws_size, graph-capture safe.
__device__ float g_P[(size_t)2 * VOCAB * 192];   // 77.2 MB, input-projected vocab table (bias folded)
__device__ float g_feats[BATCH * 256];           // pooled features

__device__ __forceinline__ float fast_rcp(float x) { return __builtin_amdgcn_rcpf(x); }

__device__ __forceinline__ float fsigmoid(float x) {
    // 1/(1+exp(-x)); saturates correctly at +-inf
    return fast_rcp(1.f + __expf(-x));
}
__device__ __forceinline__ float ftanh(float x) {
    // 1 - 2/(exp(2x)+1); saturates correctly at +-inf
    float e = __expf(2.f * x);
    return 1.f - 2.f * fast_rcp(e + 1.f);
}

// ---------------- Kernel A: P[dir][v][g] = dot(emb[v], wih[dir][g]) + bih[dir][g] ----------------
// 2-way v-unroll: two independent 64-deep FMA chains per iteration (ILP vs the 4-cyc dep latency).
__global__ __launch_bounds__(384) void precompute_P(
    const float* __restrict__ emb,
    const float* __restrict__ wih_f, const float* __restrict__ bih_f,
    const float* __restrict__ wih_b, const float* __restrict__ bih_b)
{
    const int t = threadIdx.x;          // 0..383 ; waves are uniform in (dir), contiguous in g
    const int dir = t / 192;
    const int g = t % 192;
    const float* wih = dir ? wih_b : wih_f;
    const float* bih = dir ? bih_b : bih_f;

    float w[64];
#pragma unroll
    for (int e = 0; e < 64; e += 4) {
        float4 v = *(const float4*)(wih + (size_t)g * 64 + e);
        w[e] = v.x; w[e + 1] = v.y; w[e + 2] = v.z; w[e + 3] = v.w;
    }
    const float bias = bih[g];
    float* Pd = g_P + (size_t)dir * VOCAB * 192;

    for (int v = blockIdx.x * 2; v < VOCAB; v += gridDim.x * 2) {
        const int v1ok = (v + 1 < VOCAB);
        const float4* e0 = (const float4*)(emb + (size_t)v * 64);            // wave-uniform -> scalar loads
        const float4* e1 = (const float4*)(emb + (size_t)(v1ok ? v + 1 : v) * 64);
        float a0 = bias, a1 = bias;
#pragma unroll
        for (int e4 = 0; e4 < 16; e4++) {
            float4 x = e0[e4];
            float4 y = e1[e4];
            a0 = fmaf(x.x, w[4 * e4 + 0], a0);
            a1 = fmaf(y.x, w[4 * e4 + 0], a1);
            a0 = fmaf(x.y, w[4 * e4 + 1], a0);
            a1 = fmaf(y.y, w[4 * e4 + 1], a1);
            a0 = fmaf(x.z, w[4 * e4 + 2], a0);
            a1 = fmaf(y.z, w[4 * e4 + 2], a1);
            a0 = fmaf(x.w, w[4 * e4 + 3], a0);
            a1 = fmaf(y.w, w[4 * e4 + 3], a1);
        }
        Pd[(size_t)v * 192 + g] = a0;
        if (v1ok) Pd[(size_t)(v + 1) * 192 + g] = a1;
    }
}

// ---------------- Kernel B: one wave per (dir, batch) sequence; fused mean/max pooling ----------------
// Single wave64 per block => lockstep execution; LDS ops from one wave complete in order, so NO
// __syncthreads() is needed for the h broadcast. Critically, __syncthreads() lowers to
// "s_waitcnt vmcnt(0) lgkmcnt(0); s_barrier", and the per-step vmcnt(0) drain was killing the
// xg prefetch pipeline (every step paid full random L3/HBM latency into the 77MB P table).
__global__ __launch_bounds__(64, 1) void gru_seq(
    const int* __restrict__ tokens,
    const float* __restrict__ whh_f, const float* __restrict__ bhh_f,
    const float* __restrict__ whh_b, const float* __restrict__ bhh_b)
{
    const int lane = threadIdx.x;        // hidden unit index
    const int blk = blockIdx.x;          // 0..255
    const int b = blk >> 1;
    const int dir = blk & 1;
    const float* whh = dir ? whh_b : whh_f;
    const float* bhh = dir ? bhh_b : bhh_f;
    const float* Pd = g_P + (size_t)dir * VOCAB * 192;

    __shared__ __align__(16) float h_lds[64];
    __shared__ __align__(16) int tok_lds[TLEN];

    // stage token row (8 KB) once, vectorized: 512 int4 across 64 lanes = 8 iterations
    {
        const int4* src = (const int4*)(tokens + (size_t)b * TLEN);
        int4* dst = (int4*)tok_lds;
        for (int t = lane; t < TLEN / 4; t += 64) dst[t] = src[t];
    }

    // per-lane whh rows (r,z,n) -> 192 VGPRs as v2f
    v2f wr[32], wz[32], wn[32];
    {
        const float* pr = whh + (size_t)(0 + lane) * 64;
        const float* pz = whh + (size_t)(64 + lane) * 64;
        const float* pn = whh + (size_t)(128 + lane) * 64;
#pragma unroll
        for (int k = 0; k < 16; k++) {
            float4 a = *(const float4*)(pr + 4 * k);
            wr[2 * k] = (v2f){a.x, a.y}; wr[2 * k + 1] = (v2f){a.z, a.w};
            float4 c = *(const float4*)(pz + 4 * k);
            wz[2 * k] = (v2f){c.x, c.y}; wz[2 * k + 1] = (v2f){c.z, c.w};
            float4 d = *(const float4*)(pn + 4 * k);
            wn[2 * k] = (v2f){d.x, d.y}; wn[2 * k + 1] = (v2f){d.z, d.w};
        }
    }
    const float br = bhh[lane], bz = bhh[64 + lane], bn = bhh[128 + lane];

    h_lds[lane] = 0.f;
    float h = 0.f, sum = 0.f, mx = -INFINITY;
    // no barrier: single wave, lockstep; LDS unit processes this wave's ops in order

    // time mapping: step s -> tt = dir ? T-1-s : s (backward dir feeds reversed sequence)
    auto tok_at = [&](int s) -> int {
        int ss = s < TLEN ? s : TLEN - 1;        // clamp for tail prefetches (values unused)
        return tok_lds[dir ? (TLEN - 1 - ss) : ss];
    };

    // xg prefetch ring, depth 4 (~4 steps of latency cover), slot = s & 3 stays
    // compile-time-constant under the unroll-4 so the ring lives in registers.
    float xr[4], xz[4], xn[4];
#pragma unroll
    for (int d = 0; d < 4; d++) {
        const float* rd = Pd + (size_t)tok_at(d) * 192;
        xr[d] = rd[lane]; xz[d] = rd[64 + lane]; xn[d] = rd[128 + lane];
    }
    int tokN = tok_at(4);   // token index for step s+4, read one iteration ahead

#pragma unroll 4
    for (int s = 0; s < TLEN; s++) {
        const int slot = s & 3;

        // issue prefetch for step s+4 (address already resolved last iteration)
        const float* rp = Pd + (size_t)tokN * 192;
        float pxr = rp[lane], pxz = rp[64 + lane], pxn = rp[128 + lane];
        tokN = tok_at(s + 5);   // ds_read consumed next iteration (off critical path)

        // hg dots over h (LDS broadcast, b128 reads), 2 packed accumulators per gate
        v2f ar0 = {0.f, 0.f}, ar1 = {0.f, 0.f};
        v2f az0 = {0.f, 0.f}, az1 = {0.f, 0.f};
        v2f an0 = {0.f, 0.f}, an1 = {0.f, 0.f};
#pragma unroll
        for (int k = 0; k < 16; k++) {
            float4 h4 = *(const float4*)(h_lds + 4 * k);
            v2f h01 = {h4.x, h4.y}, h23 = {h4.z, h4.w};
            ar0 = __builtin_elementwise_fma(h01, wr[2 * k], ar0);
            az0 = __builtin_elementwise_fma(h01, wz[2 * k], az0);
            an0 = __builtin_elementwise_fma(h01, wn[2 * k], an0);
            ar1 = __builtin_elementwise_fma(h23, wr[2 * k + 1], ar1);
            az1 = __builtin_elementwise_fma(h23, wz[2 * k + 1], az1);
            an1 = __builtin_elementwise_fma(h23, wn[2 * k + 1], an1);
        }
        float hr = (ar0.x + ar0.y) + (ar1.x + ar1.y);
        float hz = (az0.x + az0.y) + (az1.x + az1.y);
        float hn = (an0.x + an0.y) + (an1.x + an1.y);

        float r = fsigmoid(xr[slot] + hr + br);
        float z = fsigmoid(xz[slot] + hz + bz);
        float n = ftanh(xn[slot] + r * (hn + bn));
        h = fmaf(z, h - n, n);               // (1-z)*n + z*h
        sum += h;
        mx = fmaxf(mx, h);

        // publish h for next step; wave-lockstep + in-order LDS make this safe without a barrier
        h_lds[lane] = h;

        // refill the slot just consumed (next use at s+4)
        xr[slot] = pxr; xz[slot] = pxz; xn[slot] = pxn;
    }

    // feats layout [b][256]: [mean_f | mean_b | max_f | max_b]
    g_feats[b * 256 + dir * 64 + lane] = sum * (1.f / TLEN);
    g_feats[b * 256 + 128 + dir * 64 + lane] = mx;
}

// ---------------- Kernel C: classifier  out = W2 @ gelu(W1 @ feats + b1) + b2 ----------------
__global__ __launch_bounds__(64) void classifier(
    const float* __restrict__ w1, const float* __restrict__ b1,
    const float* __restrict__ w2, const float* __restrict__ b2,
    float* __restrict__ out)
{
    const int b = blockIdx.x;
    const int i = threadIdx.x;
    __shared__ float f[256];
    __shared__ float hid[64];
    for (int c = i; c < 256; c += 64) f[c] = g_feats[b * 256 + c];
    __syncthreads();

    float acc = b1[i];
    const float* wrow = w1 + (size_t)i * 256;
#pragma unroll 16
    for (int c = 0; c < 256; c++) acc = fmaf(f[c], wrow[c], acc);
    // exact GELU: x * 0.5 * (1 + erf(x/sqrt(2)))
    hid[i] = acc * 0.5f * (1.f + erff(acc * 0.70710678118654752f));
    __syncthreads();

    if (i < NCLS) {
        float o = b2[i];
        const float* w2r = w2 + (size_t)i * 64;
#pragma unroll
        for (int j = 0; j < 64; j++) o = fmaf(hid[j], w2r[j], o);
        out[b * NCLS + i] = o;
    }
}

extern "C" void kernel_launch(void* const* d_in, const int* in_sizes, int n_in,
                              void* d_out, int out_size, void* d_ws, size_t ws_size,
                              hipStream_t stream) {
    const int*   tokens = (const int*)  d_in[0];
    const float* emb    = (const float*)d_in[1];
    const float* wih_f  = (const float*)d_in[2];
    const float* whh_f  = (const float*)d_in[3];
    const float* bih_f  = (const float*)d_in[4];
    const float* bhh_f  = (const float*)d_in[5];
    const float* wih_b  = (const float*)d_in[6];
    const float* whh_b  = (const float*)d_in[7];
    const float* bih_b  = (const float*)d_in[8];
    const float* bhh_b  = (const float*)d_in[9];
    const float* w1     = (const float*)d_in[10];
    const float* b1     = (const float*)d_in[11];
    const float* w2     = (const float*)d_in[12];
    const float* b2     = (const float*)d_in[13];
    float* out = (float*)d_out;

    precompute_P<<<1024, 384, 0, stream>>>(emb, wih_f, bih_f, wih_b, bih_b);
    gru_seq<<<2 * BATCH, 64, 0, stream>>>(tokens, whh_f, bhh_f, whh_b, bhh_b);
    classifier<<<BATCH, 64, 0, stream>>>(w1, b1, w2, b2, out);
}